// Round 10
// baseline (299.307 us; speedup 1.0000x reference)
//
#include <hip/hip_runtime.h>
#include <math.h>

typedef __bf16 bf16_t;
typedef bf16_t bf16x8 __attribute__((ext_vector_type(8)));
typedef bf16_t bf16x4 __attribute__((ext_vector_type(4)));
typedef float floatx4 __attribute__((ext_vector_type(4)));
typedef short short4v __attribute__((ext_vector_type(4)));

#define MFMA16(a, b, c) __builtin_amdgcn_mfma_f32_16x16x32_bf16((a), (b), (c), 0, 0, 0)

#if __has_builtin(__builtin_amdgcn_exp2f)
#define PEXP(x) __builtin_amdgcn_exp2f(x)
#define SCORE_SCALE (0.125f * 1.4426950408889634f)   // fold log2e into Q scale
#else
#define PEXP(x) __expf(x)
#define SCORE_SCALE 0.125f
#endif

#if __has_builtin(__builtin_amdgcn_mfma_f32_16x16x16bf16_1k)
#define HAVE_MFMA_K16 1
__device__ __forceinline__ floatx4 mfma_k16(bf16x4 a, bf16x4 b, floatx4 c)
{
    union { bf16x4 v; short4v s; } ua, ub;
    ua.v = a; ub.v = b;
    return __builtin_amdgcn_mfma_f32_16x16x16bf16_1k(ua.s, ub.s, c, 0, 0, 0);
}
#endif

union PU { unsigned u[2]; bf16x4 v; };
union BU { unsigned u[4]; bf16x8 v; };

// global -> LDS direct copy, 16 B per lane (wave-uniform LDS base + lane*16).
__device__ __forceinline__ void gld16(const void* g, void* lds)
{
    __builtin_amdgcn_global_load_lds(
        reinterpret_cast<const __attribute__((address_space(1))) void*>(
            reinterpret_cast<uintptr_t>(g)),
        reinterpret_cast<__attribute__((address_space(3))) void*>(
            (unsigned int)reinterpret_cast<uintptr_t>(lds)),
        16, 0, 0);
}

template <int N>
__device__ __forceinline__ void vmw()
{
    __asm__ volatile("s_waitcnt vmcnt(%0)" :: "n"(N) : "memory");
}

__device__ __forceinline__ void barx()
{
    __asm__ volatile("" ::: "memory");
    __builtin_amdgcn_s_barrier();
    __asm__ volatile("" ::: "memory");
}

__device__ __forceinline__ void lgk0()
{
    __asm__ volatile("s_waitcnt lgkmcnt(0)" ::: "memory");
}

// ---------------------------------------------------------------------------
// Quadrant-phased 256-row GEMM (m201-style interleave, corrected waits).
// C[M,N]=A[M,K]@Bt[N,K]^T. BM=256, BN in {256,128}; 512 thr = 8 waves (2Mx4N);
// per-wave 128 x BN/4. BK=64. LDS: A[2][256][64] + B[2][BN][64], XOR-swizzled.
// Per K-tile u, FOUR phases, each {issue ds_reads -> issue 1 stage unit ->
// barrier -> lgkmcnt(0) -> setprio(1) 16 MFMA setprio(0) -> barrier}:
//   ph0: rd A-lo + B-n0; stage B0(u+1)->other buf;  MFMA acc[0-3][n0]
//   ph1: rd B-n1;        stage B1(u+1)->other buf;  MFMA acc[0-3][n1]
//   ph2: rd A-hi;        (no stage);                MFMA acc[4-7][n1]
//   ph3: rd B-n0 again;  stage A(u+2)->CURRENT buf; MFMA acc[4-7][n0]
// ONE counted vmcnt per K-tile, at ph3 after the A-stage: issue order is
// ..., A(u+1)@ph3(u-1)[4], B0(u+1)@ph0(u)[2RBH], B1(u+1)@ph1(u)[2RBH],
// A(u+2)@ph3(u)[4] -> vmcnt(4) leaves exactly A(u+2) and retires ALL of
// tile u+1 before any wave reads it (post-ph3 barrier). Never vmcnt(0)
// in the main loop. A(u+2) overwrites current-buf A only after ph2's last
// A-read retired (ph2 lgkm0 + barrier). B(u+1) targets the other buffer,
// whose readers finished at tile entry.
// ---------------------------------------------------------------------------
template <typename TC, int BN>
__device__ __forceinline__ void gemm_ph_body(
    const bf16_t* __restrict__ A, const bf16_t* __restrict__ Bt,
    TC* __restrict__ C, int row0, int col0, int N, int K, bf16_t* smem)
{
    constexpr int NT  = BN / 64;     // per-wave n-frags: 4 or 2
    constexpr int NH  = NT / 2;      // n-frags per phase: 2 or 1
    constexpr int RBH = BN / 128;    // gld16 rounds per B half: 2 or 1

    const int tid  = threadIdx.x;
    const int wave = tid >> 6, lane = tid & 63;
    const int quad = lane >> 4, l16 = lane & 15;
    const int wm = (wave >> 2) * 128;
    const int wn = (wave & 3) * (BN / 4);

    bf16_t* As0 = smem;
    bf16_t* As1 = smem + 256 * 64;
    bf16_t* Bs0 = smem + 2 * 256 * 64;
    bf16_t* Bs1 = Bs0 + BN * 64;

    const int ntile = K >> 6;

    floatx4 acc[8][NT] = {};
    bf16x8  af[4][2];            // A m-frags for current half-phase (reused)
    bf16x8  bfr[NH][2];          // B n-half0 frags
    bf16x8  bf1[NH][2];          // B n-half1 frags

#define PH_STG_A(Bf, h, uu) do {                                              \
    _Pragma("unroll")                                                         \
    for (int _i = 0; _i < 2; ++_i) {                                          \
        int _c = _i * 512 + tid, _r = (h) * 128 + (_c >> 3), _s = _c & 7;     \
        gld16(A + (size_t)(row0 + _r) * K + ((uu) << 6)                       \
                + ((_s ^ (_r & 7)) << 3),                                     \
              (Bf) + (h) * 8192 + (_i * 512 + wave * 64) * 8);                \
    } } while (0)

#define PH_STG_B(Bf, h, uu) do {                                              \
    _Pragma("unroll")                                                         \
    for (int _i = 0; _i < RBH; ++_i) {                                        \
        int _c = _i * 512 + tid, _r = (h) * (BN / 2) + (_c >> 3), _s = _c & 7;\
        gld16(Bt + (size_t)(col0 + _r) * K + ((uu) << 6)                      \
                 + ((_s ^ (_r & 7)) << 3),                                    \
              (Bf) + (h) * (BN / 2) * 64 + (_i * 512 + wave * 64) * 8);       \
    } } while (0)

#define PH_RD_A(MH) do {                                                      \
    _Pragma("unroll")                                                         \
    for (int _i = 0; _i < 4; ++_i)                                            \
        _Pragma("unroll")                                                     \
        for (int _kh = 0; _kh < 2; ++_kh) {                                   \
            int _ar = wm + ((MH) * 4 + _i) * 16 + l16;                        \
            af[_i][_kh] = *(const bf16x8*)&Asd[_ar * 64 +                     \
                (((_kh * 4 + quad) ^ (_ar & 7)) << 3)];                       \
        } } while (0)

#define PH_RD_B(Reg, NF) do {                                                 \
    _Pragma("unroll")                                                         \
    for (int _j = 0; _j < NH; ++_j)                                           \
        _Pragma("unroll")                                                     \
        for (int _kh = 0; _kh < 2; ++_kh) {                                   \
            int _br = wn + ((NF) * NH + _j) * 16 + l16;                       \
            Reg[_j][_kh] = *(const bf16x8*)&Bsd[_br * 64 +                    \
                (((_kh * 4 + quad) ^ (_br & 7)) << 3)];                       \
        } } while (0)

#define PH_MM(MB, Reg, NF) do {                                               \
    __builtin_amdgcn_s_setprio(1);                                            \
    _Pragma("unroll")                                                         \
    for (int _kh = 0; _kh < 2; ++_kh)                                         \
        _Pragma("unroll")                                                     \
        for (int _i = 0; _i < 4; ++_i)                                        \
            _Pragma("unroll")                                                 \
            for (int _j = 0; _j < NH; ++_j)                                   \
                acc[(MB) * 4 + _i][(NF) * NH + _j] =                          \
                    MFMA16(af[_i][_kh], Reg[_j][_kh],                         \
                           acc[(MB) * 4 + _i][(NF) * NH + _j]);               \
    __builtin_amdgcn_s_setprio(0);                                            \
} while (0)

    // prologue: tile0 (A both halves, B both halves) + tile1 A (4 newest)
    PH_STG_A(As0, 0, 0); PH_STG_A(As0, 1, 0);
    PH_STG_B(Bs0, 0, 0); PH_STG_B(Bs0, 1, 0);
    PH_STG_A(As1, 0, 1); PH_STG_A(As1, 1, 1);
    vmw<4>();            // tile0 landed (this wave); A(1) in flight
    barx();              // landed for ALL waves

    #pragma unroll 1
    for (int u = 0; u < ntile; ++u) {
        const int d = u & 1;
        bf16_t* Asd = d ? As1 : As0;
        bf16_t* Bsd = d ? Bs1 : Bs0;
        bf16_t* Bsn = d ? Bs0 : Bs1;
        const bool nl1 = (u + 1 < ntile);
        const bool nl2 = (u + 2 < ntile);

        // ---- phase 0: quadrant (m-lo, n0)
        PH_RD_A(0);
        PH_RD_B(bfr, 0);
        if (nl1) PH_STG_B(Bsn, 0, u + 1);
        barx(); lgk0();
        PH_MM(0, bfr, 0);
        barx();

        // ---- phase 1: quadrant (m-lo, n1)   (af held)
        PH_RD_B(bf1, 1);
        if (nl1) PH_STG_B(Bsn, 1, u + 1);
        barx(); lgk0();
        PH_MM(0, bf1, 1);
        barx();

        // ---- phase 2: quadrant (m-hi, n1)   (bf1 held; af reloaded)
        PH_RD_A(1);
        barx(); lgk0();
        PH_MM(1, bf1, 1);
        barx();

        // ---- phase 3: quadrant (m-hi, n0)   (bfr re-read; A(u+2) staged
        //              into CURRENT buf — all A-reads retired at ph2)
        PH_RD_B(bfr, 0);
        if (nl2) {
            PH_STG_A(Asd, 0, u + 2); PH_STG_A(Asd, 1, u + 2);
            vmw<4>();                // retires ALL of tile u+1
        } else {
            vmw<0>();                // tail: drain remaining
        }
        barx(); lgk0();
        PH_MM(1, bfr, 0);
        barx();
    }

#undef PH_STG_A
#undef PH_STG_B
#undef PH_RD_A
#undef PH_RD_B
#undef PH_MM

    #pragma unroll
    for (int mt = 0; mt < 8; ++mt)
        #pragma unroll
        for (int nt = 0; nt < NT; ++nt)
            #pragma unroll
            for (int r = 0; r < 4; ++r)
                C[(size_t)(row0 + wm + mt * 16 + quad * 4 + r) * N
                  + col0 + wn + nt * 16 + l16] = (TC)acc[mt][nt][r];
}

// Fused Q+K+V projection. grid.x = 12: 0..7 -> Q, 8..9 -> K, 10..11 -> V.
__global__ __launch_bounds__(512, 2) void gemm256_qkv(
    const bf16_t* __restrict__ A, const bf16_t* __restrict__ BtQ,
    const bf16_t* __restrict__ BtK, const bf16_t* __restrict__ BtV,
    bf16_t* __restrict__ CQ, bf16_t* __restrict__ CK, bf16_t* __restrict__ CV)
{
    extern __shared__ __align__(16) bf16_t smem[];
    const int x = blockIdx.x;
    const bf16_t* Bt; bf16_t* C; int N, col0;
    if (x < 8)       { Bt = BtQ; C = CQ; N = 2048; col0 = x * 256; }
    else if (x < 10) { Bt = BtK; C = CK; N = 512;  col0 = (x - 8) * 256; }
    else             { Bt = BtV; C = CV; N = 512;  col0 = (x - 10) * 256; }
    gemm_ph_body<bf16_t, 256>(A, Bt, C, blockIdx.y * 256, col0, N, 2048, smem);
}

// Output projection: BM=256, BN=128 -> grid 16x16 = 256 blocks = 1/CU.
__global__ __launch_bounds__(512, 2) void gemm256_out(
    const bf16_t* __restrict__ A, const bf16_t* __restrict__ Bt,
    float* __restrict__ C)
{
    extern __shared__ __align__(16) bf16_t smem[];
    gemm_ph_body<float, 128>(A, Bt, C, blockIdx.y * 256, blockIdx.x * 128,
                             2048, 2048, smem);
}

// ---------------------------------------------------------------------------
// Fused prep: x->bf16 conversion + Wq/Wk/Wv fp32->bf16 transposes.
// grid: [0,8192) conv, [8192,12288) Wq, [12288,13312) Wk, [13312,14336) Wv
// ---------------------------------------------------------------------------
__device__ __forceinline__ void transpose_body(
    const float* __restrict__ W, bf16_t* __restrict__ Wt, int K, int N,
    int bx, int by, float (*t)[33], int tid)
{
    int tx = tid & 31, ty = tid >> 5;
    #pragma unroll
    for (int i = 0; i < 32; i += 8)
        t[ty + i][tx] = W[(size_t)(by + ty + i) * N + bx + tx];
    __syncthreads();
    #pragma unroll
    for (int i = 0; i < 32; i += 8)
        Wt[(size_t)(bx + ty + i) * K + by + tx] = (bf16_t)t[tx][ty + i];
}

__global__ __launch_bounds__(256) void prep_all(
    const float* __restrict__ x, const float* __restrict__ Wq,
    const float* __restrict__ Wk, const float* __restrict__ Wv,
    bf16_t* __restrict__ xb, bf16_t* __restrict__ WqT,
    bf16_t* __restrict__ WkT, bf16_t* __restrict__ WvT)
{
    __shared__ float t[32][33];
    const int blk = blockIdx.x, tid = threadIdx.x;
    if (blk < 8192) {
        int i = blk * 256 + tid;
        float4 f = ((const float4*)x)[i];
        bf16x4 v = {(bf16_t)f.x, (bf16_t)f.y, (bf16_t)f.z, (bf16_t)f.w};
        ((bf16x4*)xb)[i] = v;
    } else if (blk < 12288) {
        int r = blk - 8192;
        transpose_body(Wq, WqT, 2048, 2048, (r & 63) * 32, (r >> 6) * 32, t, tid);
    } else if (blk < 13312) {
        int r = blk - 12288;
        transpose_body(Wk, WkT, 2048, 512, (r & 15) * 32, (r >> 4) * 32, t, tid);
    } else {
        int r = blk - 13312;
        transpose_body(Wv, WvT, 2048, 512, (r & 15) * 32, (r >> 4) * 32, t, tid);
    }
}

// ---------------------------------------------------------------------------
// Fused mid: RoPE(K) + V-transpose + Wo-transpose.
// grid: [0,4096) rope, [4096,6144) V^T, [6144,10240) Wo
// ---------------------------------------------------------------------------
__global__ __launch_bounds__(256) void mid_all(
    bf16_t* __restrict__ Kw, const bf16_t* __restrict__ Vw,
    bf16_t* __restrict__ VtG, const float* __restrict__ Wo,
    bf16_t* __restrict__ WoT)
{
    __shared__ float tf[32][33];
    __shared__ bf16_t tb[32][34];
    const int blk = blockIdx.x, tid = threadIdx.x;
    if (blk < 4096) {
        int idx = blk * 256 + tid;
        int i   = idx & 31;
        int h   = (idx >> 5) & 7;
        int row = idx >> 8;
        int pos = row & 2047;
        float invf = powf(10000.0f, -(float)i / 32.0f);
        float sv, cv;
        sincosf((float)pos * invf, &sv, &cv);
        size_t base = (size_t)row * 512 + (size_t)h * 64 + i;
        float a  = (float)Kw[base];
        float b2 = (float)Kw[base + 32];
        Kw[base]      = (bf16_t)(a * cv - b2 * sv);
        Kw[base + 32] = (bf16_t)(b2 * cv + a * sv);
    } else if (blk < 6144) {
        int r  = blk - 4096;
        int bz = r >> 10, r2 = r & 1023;
        int bx = (r2 & 15) * 32, by = (r2 >> 4) * 32;
        int tx = tid & 31, ty = tid >> 5;
        #pragma unroll
        for (int i = 0; i < 32; i += 8)
            tb[ty + i][tx] = Vw[((size_t)bz * 2048 + by + ty + i) * 512 + bx + tx];
        __syncthreads();
        #pragma unroll
        for (int i = 0; i < 32; i += 8)
            VtG[((size_t)bz * 512 + bx + ty + i) * 2048 + by + tx] = tb[tx][ty + i];
    } else {
        int r = blk - 6144;
        transpose_body(Wo, WoT, 2048, 2048, (r & 63) * 32, (r >> 6) * 32, tf, tid);
    }
}

// ---------------------------------------------------------------------------
// Causal GQA flash attention, GROUP-SHARED K/V + XCD-PINNED GROUPS,
// KVBLK=128 fat windows. (byte-identical to round 9 — 81.7 us measured)
// ---------------------------------------------------------------------------
__global__ __launch_bounds__(256, 2) void gqa_attn(
    const bf16_t* __restrict__ Q, const bf16_t* __restrict__ Kc,
    const bf16_t* __restrict__ Vt, bf16_t* __restrict__ AO)
{
    __shared__ alignas(16) bf16_t Ks[2][128 * 64];  // [buf][2x 64x64 swizzled]
    __shared__ alignas(16) bf16_t Vs[2][128 * 64];  // [buf][2x 64d x 64k swz]

    const int bid = blockIdx.x;
    const int l   = (bid & 7) * 64 + (bid >> 3);   // XCD-pinning remap
    const int g   = l >> 6;                        // kv-group == XCD
    const int b   = (l >> 5) & 1;
    const int x   = l & 31;

    const int tid  = threadIdx.x;
    const int wave = tid >> 6, lane = tid & 63;
    const int quad = lane >> 4, l16 = lane & 15;
    const int h = g * 4 + wave;                // each wave owns one head

    #pragma unroll 1
    for (int t = 0; t < 2; ++t) {
        const int qt = t ? x : (63 - x);       // 32-row tile idx, heavy first
        const int q0 = qt * 32;
        int qb[2];
        qb[0] = q0;
        qb[1] = q0 + 16;

        // Q as B-frag (Q^T): lane holds Q[qb+l16][kh*32+quad*8+j], RoPE+scale
        bf16x8 qf[2][2];
        #pragma unroll
        for (int mt = 0; mt < 2; ++mt) {
            int qrow = qb[mt] + l16;
            const bf16_t* qp = Q + (size_t)(b * 2048 + qrow) * 2048 + h * 64 + quad * 8;
            bf16x8 lo = *(const bf16x8*)qp;
            bf16x8 hi = *(const bf16x8*)(qp + 32);
            #pragma unroll
            for (int j = 0; j < 8; ++j) {
                int d = quad * 8 + j;
                float invf = powf(10000.0f, -(float)d / 32.0f);
                float sv, cv;
                sincosf((float)qrow * invf, &sv, &cv);
                float a = (float)lo[j], c2 = (float)hi[j];
                qf[mt][0][j] = (bf16_t)((a * cv - c2 * sv) * SCORE_SCALE);
                qf[mt][1][j] = (bf16_t)((c2 * cv + a * sv) * SCORE_SCALE);
            }
        }

        floatx4 o[2][4] = {};     // O^T: [mt][dt], rows d=quad*4+r, col q=l16
        floatx4 ls4[2] = {};      // lsum partials per q=l16 (4 chains)

        const int ktmax = qt >> 1;             // last valid 64-key tile
        const int nwin  = (ktmax >> 1) + 1;    // 128-key windows

        // stage window `win` (128 keys) into buffer dst: 4 K + 4 V rounds
        auto STAGE = [&](int win, int dst) {
            const int kbase = win * 128;
            #pragma unroll
            for (int i = 0; i < 4; ++i) {       // K rows kbase..kbase+127
                int c = i * 256 + tid, r = c >> 3, s = c & 7;
                int sw = (s ^ (r & 7)) << 3;
                gld16(Kc + (size_t)(b * 2048 + kbase + r) * 512 + g * 64 + sw,
                      &Ks[dst][(i * 256 + wave * 64) * 8]);
            }
            #pragma unroll
            for (int i = 0; i < 4; ++i) {       // V^T: d-rows x 2 key-halves
                int c = i * 256 + tid;
                int ci = c & 511, hw = c >> 9;
                int r = ci >> 3, s = ci & 7;
                int sw = (s ^ (r & 7)) << 3;
                gld16(Vt + (size_t)(b * 512 + g * 64 + r) * 2048
                         + kbase + hw * 64 + sw,
                      &Vs[dst][(i * 256 + wave * 64) * 8]);
            }
        };

        // prologue: buffers free (prev tile drained), prefetch window 0
        __asm__ volatile("s_waitcnt lgkmcnt(0)" ::: "memory");
        __builtin_amdgcn_s_barrier();
        STAGE(0, 0);

        #pragma unroll 1
        for (int win = 0; win < nwin; ++win) {
            const int cur = win & 1;
            if (win + 1 < nwin) {
                STAGE(win + 1, cur ^ 1);
                __asm__ volatile("s_waitcnt vmcnt(8)" ::: "memory");
            } else {
                __asm__ volatile("s_waitcnt vmcnt(0)" ::: "memory");
            }
            __builtin_amdgcn_s_barrier();   // buf[cur] fully landed

            #pragma unroll
            for (int hw = 0; hw < 2; ++hw) {
                const int kt = 2 * win + hw;
                if (kt <= ktmax) {
                    const bf16_t* Ksh = &Ks[cur][hw * 4096];
                    const bf16_t* Vsh = &Vs[cur][hw * 4096];

                    // S^T = K.Q^T
                    floatx4 st[2][4] = {};
                    __builtin_amdgcn_s_setprio(1);
                    #pragma unroll
                    for (int nt = 0; nt < 4; ++nt) {
                        int kr = nt * 16 + l16;
                        bf16x8 kf0 = *(const bf16x8*)&Ksh[kr * 64 + ((quad ^ (kr & 7)) << 3)];
                        bf16x8 kf1 = *(const bf16x8*)&Ksh[kr * 64 + (((4 + quad) ^ (kr & 7)) << 3)];
                        st[0][nt] = MFMA16(kf0, qf[0][0], st[0][nt]);
                        st[0][nt] = MFMA16(kf1, qf[0][1], st[0][nt]);
                        st[1][nt] = MFMA16(kf0, qf[1][0], st[1][nt]);
                        st[1][nt] = MFMA16(kf1, qf[1][1], st[1][nt]);
                    }
                    __builtin_amdgcn_s_setprio(0);

                    // exp2 + causal mask (diag tile only) + lsum + pack P^T
                    PU pk[2][4];
                    const bool diag = (kt == ktmax);
                    #pragma unroll
                    for (int mt = 0; mt < 2; ++mt) {
                        const int qa = qb[mt] + l16;
                        #pragma unroll
                        for (int nt = 0; nt < 4; ++nt) {
                            float pv[4];
                            #pragma unroll
                            for (int r = 0; r < 4; ++r) {
                                float e = PEXP(st[mt][nt][r]);
                                if (diag) {
                                    int ka = kt * 64 + nt * 16 + quad * 4 + r;
                                    if (ka > qa) e = 0.f;
                                }
                                ls4[mt][r] += e;
                                pv[r] = e;
                            }
                            pk[mt][nt].v = bf16x4{(bf16_t)pv[0], (bf16_t)pv[1],
                                                  (bf16_t)pv[2], (bf16_t)pv[3]};
                        }
                    }

#ifdef HAVE_MFMA_K16
                    // O^T += V^T.P^T  (P^T straight from registers)
                    __builtin_amdgcn_s_setprio(1);
                    #pragma unroll
                    for (int nt = 0; nt < 4; ++nt)
                        #pragma unroll
                        for (int dt = 0; dt < 4; ++dt) {
                            int vr = dt * 16 + l16;
                            int slot = ((nt << 1) | (quad >> 1)) ^ (vr & 7);
                            bf16x4 va = *(const bf16x4*)&Vsh[vr * 64 + (slot << 3)
                                                             + ((quad & 1) << 2)];
                            o[0][dt] = mfma_k16(va, pk[0][nt].v, o[0][dt]);
                            o[1][dt] = mfma_k16(va, pk[1][nt].v, o[1][dt]);
                        }
                    __builtin_amdgcn_s_setprio(0);
#else
                    #pragma unroll
                    for (int H = 0; H < 2; ++H) {
                        BU bfv[2];
                        #pragma unroll
                        for (int mt = 0; mt < 2; ++mt) {
                            #pragma unroll
                            for (int j = 0; j < 4; ++j) {
                                int srcl = (((quad & 1) << 1) + (j >> 1)) * 16 + l16;
                                unsigned a0 = (unsigned)__shfl((int)pk[mt][2 * H].u[j & 1], srcl, 64);
                                unsigned a1 = (unsigned)__shfl((int)pk[mt][2 * H + 1].u[j & 1], srcl, 64);
                                bfv[mt].u[j] = (quad >> 1) ? a1 : a0;
                            }
                        }
                        #pragma unroll
                        for (int dt = 0; dt < 4; ++dt) {
                            int vr = dt * 16 + l16;
                            bf16x8 va = *(const bf16x8*)&Vsh[vr * 64
                                          + ((((H << 2) | quad) ^ (vr & 7)) << 3)];
                            o[0][dt] = MFMA16(va, bfv[0].v, o[0][dt]);
                            o[1][dt] = MFMA16(va, bfv[1].v, o[1][dt]);
                        }
                    }
#endif
                }
            }

            // reads of buf[cur] retired before anyone overwrites it
            __asm__ volatile("s_waitcnt lgkmcnt(0)" ::: "memory");
            __builtin_amdgcn_s_barrier();
        }

        // epilogue: finish lsum (sum 4 chains + quad reduce), divide, store
        #pragma unroll
        for (int mt = 0; mt < 2; ++mt) {
            float l2 = ls4[mt][0] + ls4[mt][1] + ls4[mt][2] + ls4[mt][3];
            l2 += __shfl_xor(l2, 16, 64);
            l2 += __shfl_xor(l2, 32, 64);
            float rc = 1.0f / l2;
            #pragma unroll
            for (int dt = 0; dt < 4; ++dt) {
                bf16x4 ov = {(bf16_t)(o[mt][dt][0] * rc), (bf16_t)(o[mt][dt][1] * rc),
                             (bf16_t)(o[mt][dt][2] * rc), (bf16_t)(o[mt][dt][3] * rc)};
                *(bf16x4*)&AO[(size_t)(b * 2048 + qb[mt] + l16) * 2048
                              + h * 64 + dt * 16 + quad * 4] = ov;
            }
        }
    }
}

// ---------------------------------------------------------------------------
extern "C" void kernel_launch(void* const* d_in, const int* in_sizes, int n_in,
                              void* d_out, int out_size, void* d_ws, size_t ws_size,
                              hipStream_t stream)
{
    const float* x  = (const float*)d_in[0];
    const float* Wq = (const float*)d_in[1];
    const float* Wk = (const float*)d_in[2];
    const float* Wv = (const float*)d_in[3];
    const float* Wo = (const float*)d_in[4];
    float* out = (float*)d_out;

    const size_t MB = 1024 * 1024;
    char* ws = (char*)d_ws;
    bf16_t* xb_AO = (bf16_t*)(ws);              // 16 MiB: xb, later AO
    bf16_t* WqoT  = (bf16_t*)(ws + 16 * MB);    //  8 MiB: Wq^T, later Wo^T
    bf16_t* WkT   = (bf16_t*)(ws + 24 * MB);    //  2 MiB
    bf16_t* WvT   = (bf16_t*)(ws + 26 * MB);    //  2 MiB
    bf16_t* Qw    = (bf16_t*)(ws + 28 * MB);    // 16 MiB
    bf16_t* Kw    = (bf16_t*)(ws + 44 * MB);    //  4 MiB
    bf16_t* Vw    = (bf16_t*)(ws + 48 * MB);    //  4 MiB
    bf16_t* VtG   = (bf16_t*)(ws + 52 * MB);    //  4 MiB

    // one-time: allow >64 KiB dynamic LDS on the 256-tile GEMMs
    static bool s_attr = false;
    if (!s_attr) {
        hipFuncSetAttribute(reinterpret_cast<const void*>(gemm256_qkv),
                            hipFuncAttributeMaxDynamicSharedMemorySize, 131072);
        hipFuncSetAttribute(reinterpret_cast<const void*>(gemm256_out),
                            hipFuncAttributeMaxDynamicSharedMemorySize, 98304);
        s_attr = true;
    }

    // 1) prep: x->bf16, Wq/Wk/Wv -> transposed bf16
    prep_all<<<14336, 256, 0, stream>>>(x, Wq, Wk, Wv, xb_AO, WqoT, WkT, WvT);

    // 2) fused QKV projection (quadrant-phased 256x256 tiles, 12x16 grid)
    gemm256_qkv<<<dim3(12, 16), 512, 131072, stream>>>(
        xb_AO, WqoT, WkT, WvT, Qw, Kw, Vw);

    // 3) RoPE(K) + V->V^T + Wo^T (Wo^T reuses Wq^T region, dead after QKV)
    mid_all<<<10240, 256, 0, stream>>>(Kw, Vw, VtG, Wo, WqoT);

    // 4) attention: group-shared K/V, XCD-pinned, 128-key fat windows
    gqa_attn<<<dim3(512), 256, 0, stream>>>(Qw, Kw, VtG, xb_AO);

    // 5) output projection (quadrant-phased 256x128 tiles, 16x16 grid)
    gemm256_out<<<dim3(16, 16), 512, 98304, stream>>>(xb_AO, WqoT, out);
}

// Round 11
// 288.072 us; speedup vs baseline: 1.0390x; 1.0390x over previous
//
#include <hip/hip_runtime.h>
#include <math.h>

typedef __bf16 bf16_t;
typedef bf16_t bf16x8 __attribute__((ext_vector_type(8)));
typedef bf16_t bf16x4 __attribute__((ext_vector_type(4)));
typedef float floatx4 __attribute__((ext_vector_type(4)));
typedef short short4v __attribute__((ext_vector_type(4)));

#define MFMA16(a, b, c) __builtin_amdgcn_mfma_f32_16x16x32_bf16((a), (b), (c), 0, 0, 0)

#if __has_builtin(__builtin_amdgcn_exp2f)
#define PEXP(x) __builtin_amdgcn_exp2f(x)
#define SCORE_SCALE (0.125f * 1.4426950408889634f)   // fold log2e into Q scale
#else
#define PEXP(x) __expf(x)
#define SCORE_SCALE 0.125f
#endif

#if __has_builtin(__builtin_amdgcn_mfma_f32_16x16x16bf16_1k)
#define HAVE_MFMA_K16 1
__device__ __forceinline__ floatx4 mfma_k16(bf16x4 a, bf16x4 b, floatx4 c)
{
    union { bf16x4 v; short4v s; } ua, ub;
    ua.v = a; ub.v = b;
    return __builtin_amdgcn_mfma_f32_16x16x16bf16_1k(ua.s, ub.s, c, 0, 0, 0);
}
#endif

union PU { unsigned u[2]; bf16x4 v; };
union BU { unsigned u[4]; bf16x8 v; };

// global -> LDS direct copy, 16 B per lane (wave-uniform LDS base + lane*16).
__device__ __forceinline__ void gld16(const void* g, void* lds)
{
    __builtin_amdgcn_global_load_lds(
        reinterpret_cast<const __attribute__((address_space(1))) void*>(
            reinterpret_cast<uintptr_t>(g)),
        reinterpret_cast<__attribute__((address_space(3))) void*>(
            (unsigned int)reinterpret_cast<uintptr_t>(lds)),
        16, 0, 0);
}

template <int N>
__device__ __forceinline__ void vmw()
{
    __asm__ volatile("s_waitcnt vmcnt(%0)" :: "n"(N) : "memory");
}

__device__ __forceinline__ void barx()
{
    __asm__ volatile("" ::: "memory");
    __builtin_amdgcn_s_barrier();
    __asm__ volatile("" ::: "memory");
}

__device__ __forceinline__ void lgk0()
{
    __asm__ volatile("s_waitcnt lgkmcnt(0)" ::: "memory");
}

// ---------------------------------------------------------------------------
// 128x128-tile GEMM, 256 threads (4 waves 2x2), BK=64, double-buffered,
// counted vmcnt. C[M,N]=A[M,K]@Bt[N,K]^T. LDS = 64 KB -> 2 BLOCKS/CU.
// Rationale (r10 finding): the 256^2 version used 128 KB LDS = 1 block/CU
// with 25% of CUs idle (192-block grid); with a single block per CU every
// wave stalls at the same vmcnt+barrier. 128^2 restores the m97/m114
// inter-block wave overlap (2 blocks/CU, grids 768/512 blocks) that
// absorbs the barrier drain.
// Per K-tile: {stage(u+1)->other buf (8 gld16) -> vmcnt(8) -> barrier ->
// 16 ds_read_b128 -> setprio 32 MFMA -> lgkmcnt(0) -> barrier}.
// vmcnt ledger: at the wait, outstanding = tile-u's 8 + tile-(u+1)'s 8;
// vmcnt(8) retires exactly tile u. Stage targets the buffer whose readers
// retired at the previous tile's trailing lgkm0+barrier.
// ---------------------------------------------------------------------------
__device__ __forceinline__ void stage128(
    const bf16_t* __restrict__ g, int K, int r0, int k0,
    bf16_t* lds, int tid, int wave)
{
    #pragma unroll
    for (int i = 0; i < 4; ++i) {
        int c = i * 256 + tid, r = c >> 3, s = c & 7;
        gld16(g + (size_t)(r0 + r) * K + k0 + ((s ^ (r & 7)) << 3),
              lds + (size_t)(i * 256 + wave * 64) * 8);
    }
}

template <typename TC>
__device__ __forceinline__ void gemm128_body(
    const bf16_t* __restrict__ A, const bf16_t* __restrict__ Bt,
    TC* __restrict__ C, int row0, int col0, int N, int K, bf16_t* smem)
{
    const int tid  = threadIdx.x;
    const int wave = tid >> 6, lane = tid & 63;
    const int quad = lane >> 4, l16 = lane & 15;
    const int wm = (wave >> 1) * 64;
    const int wn = (wave & 1) * 64;

    bf16_t* As0 = smem;             // 128*64 each
    bf16_t* As1 = smem + 8192;
    bf16_t* Bs0 = smem + 16384;
    bf16_t* Bs1 = smem + 24576;

    const int ntile = K >> 6;

    floatx4 acc[4][4] = {};

    // prologue: tile 0 -> buf 0 (8 loads)
    stage128(A, K, row0, 0, As0, tid, wave);
    stage128(Bt, K, col0, 0, Bs0, tid, wave);

    #pragma unroll 1
    for (int u = 0; u < ntile; ++u) {
        const int d = u & 1;
        bf16_t* Asd = d ? As1 : As0;
        bf16_t* Bsd = d ? Bs1 : Bs0;

        if (u + 1 < ntile) {
            stage128(A, K, row0, (u + 1) << 6, d ? As0 : As1, tid, wave);
            stage128(Bt, K, col0, (u + 1) << 6, d ? Bs0 : Bs1, tid, wave);
            vmw<8>();               // tile u landed; tile u+1's 8 in flight
        } else {
            vmw<0>();
        }
        barx();                     // landed for ALL waves

        bf16x8 af[4][2], bfr[4][2];
        #pragma unroll
        for (int mt = 0; mt < 4; ++mt)
            #pragma unroll
            for (int kh = 0; kh < 2; ++kh) {
                int ar = wm + mt * 16 + l16;
                af[mt][kh] = *(const bf16x8*)&Asd[ar * 64 +
                    (((kh * 4 + quad) ^ (ar & 7)) << 3)];
            }
        #pragma unroll
        for (int nt = 0; nt < 4; ++nt)
            #pragma unroll
            for (int kh = 0; kh < 2; ++kh) {
                int br = wn + nt * 16 + l16;
                bfr[nt][kh] = *(const bf16x8*)&Bsd[br * 64 +
                    (((kh * 4 + quad) ^ (br & 7)) << 3)];
            }

        __builtin_amdgcn_s_setprio(1);
        #pragma unroll
        for (int kh = 0; kh < 2; ++kh)
            #pragma unroll
            for (int mt = 0; mt < 4; ++mt)
                #pragma unroll
                for (int nt = 0; nt < 4; ++nt)
                    acc[mt][nt] = MFMA16(af[mt][kh], bfr[nt][kh], acc[mt][nt]);
        __builtin_amdgcn_s_setprio(0);

        lgk0();                     // all LDS reads of buf[cur] retired
        barx();
    }

    #pragma unroll
    for (int mt = 0; mt < 4; ++mt)
        #pragma unroll
        for (int nt = 0; nt < 4; ++nt)
            #pragma unroll
            for (int r = 0; r < 4; ++r)
                C[(size_t)(row0 + wm + mt * 16 + quad * 4 + r) * N
                  + col0 + wn + nt * 16 + l16] = (TC)acc[mt][nt][r];
}

// Fused Q+K+V projection. grid (24, 32): x<16 -> Q, x<20 -> K, else V.
__global__ __launch_bounds__(256, 2) void gemm128_qkv(
    const bf16_t* __restrict__ A, const bf16_t* __restrict__ BtQ,
    const bf16_t* __restrict__ BtK, const bf16_t* __restrict__ BtV,
    bf16_t* __restrict__ CQ, bf16_t* __restrict__ CK, bf16_t* __restrict__ CV)
{
    extern __shared__ __align__(16) bf16_t smem[];
    const int x = blockIdx.x;
    const bf16_t* Bt; bf16_t* C; int N, col0;
    if (x < 16)      { Bt = BtQ; C = CQ; N = 2048; col0 = x * 128; }
    else if (x < 20) { Bt = BtK; C = CK; N = 512;  col0 = (x - 16) * 128; }
    else             { Bt = BtV; C = CV; N = 512;  col0 = (x - 20) * 128; }
    gemm128_body<bf16_t>(A, Bt, C, blockIdx.y * 128, col0, N, 2048, smem);
}

// Output projection: grid (16, 32) = 512 blocks = 2/CU, fp32 out.
__global__ __launch_bounds__(256, 2) void gemm128_out(
    const bf16_t* __restrict__ A, const bf16_t* __restrict__ Bt,
    float* __restrict__ C)
{
    extern __shared__ __align__(16) bf16_t smem[];
    gemm128_body<float>(A, Bt, C, blockIdx.y * 128, blockIdx.x * 128,
                        2048, 2048, smem);
}

// ---------------------------------------------------------------------------
// Fused prep: x->bf16 conversion + Wq/Wk/Wv fp32->bf16 transposes.
// grid: [0,8192) conv, [8192,12288) Wq, [12288,13312) Wk, [13312,14336) Wv
// ---------------------------------------------------------------------------
__device__ __forceinline__ void transpose_body(
    const float* __restrict__ W, bf16_t* __restrict__ Wt, int K, int N,
    int bx, int by, float (*t)[33], int tid)
{
    int tx = tid & 31, ty = tid >> 5;
    #pragma unroll
    for (int i = 0; i < 32; i += 8)
        t[ty + i][tx] = W[(size_t)(by + ty + i) * N + bx + tx];
    __syncthreads();
    #pragma unroll
    for (int i = 0; i < 32; i += 8)
        Wt[(size_t)(bx + ty + i) * K + by + tx] = (bf16_t)t[tx][ty + i];
}

__global__ __launch_bounds__(256) void prep_all(
    const float* __restrict__ x, const float* __restrict__ Wq,
    const float* __restrict__ Wk, const float* __restrict__ Wv,
    bf16_t* __restrict__ xb, bf16_t* __restrict__ WqT,
    bf16_t* __restrict__ WkT, bf16_t* __restrict__ WvT)
{
    __shared__ float t[32][33];
    const int blk = blockIdx.x, tid = threadIdx.x;
    if (blk < 8192) {
        int i = blk * 256 + tid;
        float4 f = ((const float4*)x)[i];
        bf16x4 v = {(bf16_t)f.x, (bf16_t)f.y, (bf16_t)f.z, (bf16_t)f.w};
        ((bf16x4*)xb)[i] = v;
    } else if (blk < 12288) {
        int r = blk - 8192;
        transpose_body(Wq, WqT, 2048, 2048, (r & 63) * 32, (r >> 6) * 32, t, tid);
    } else if (blk < 13312) {
        int r = blk - 12288;
        transpose_body(Wk, WkT, 2048, 512, (r & 15) * 32, (r >> 4) * 32, t, tid);
    } else {
        int r = blk - 13312;
        transpose_body(Wv, WvT, 2048, 512, (r & 15) * 32, (r >> 4) * 32, t, tid);
    }
}

// ---------------------------------------------------------------------------
// Fused mid: RoPE(K) + V-transpose + Wo-transpose.
// grid: [0,4096) rope, [4096,6144) V^T, [6144,10240) Wo
// ---------------------------------------------------------------------------
__global__ __launch_bounds__(256) void mid_all(
    bf16_t* __restrict__ Kw, const bf16_t* __restrict__ Vw,
    bf16_t* __restrict__ VtG, const float* __restrict__ Wo,
    bf16_t* __restrict__ WoT)
{
    __shared__ float tf[32][33];
    __shared__ bf16_t tb[32][34];
    const int blk = blockIdx.x, tid = threadIdx.x;
    if (blk < 4096) {
        int idx = blk * 256 + tid;
        int i   = idx & 31;
        int h   = (idx >> 5) & 7;
        int row = idx >> 8;
        int pos = row & 2047;
        float invf = powf(10000.0f, -(float)i / 32.0f);
        float sv, cv;
        sincosf((float)pos * invf, &sv, &cv);
        size_t base = (size_t)row * 512 + (size_t)h * 64 + i;
        float a  = (float)Kw[base];
        float b2 = (float)Kw[base + 32];
        Kw[base]      = (bf16_t)(a * cv - b2 * sv);
        Kw[base + 32] = (bf16_t)(b2 * cv + a * sv);
    } else if (blk < 6144) {
        int r  = blk - 4096;
        int bz = r >> 10, r2 = r & 1023;
        int bx = (r2 & 15) * 32, by = (r2 >> 4) * 32;
        int tx = tid & 31, ty = tid >> 5;
        #pragma unroll
        for (int i = 0; i < 32; i += 8)
            tb[ty + i][tx] = Vw[((size_t)bz * 2048 + by + ty + i) * 512 + bx + tx];
        __syncthreads();
        #pragma unroll
        for (int i = 0; i < 32; i += 8)
            VtG[((size_t)bz * 512 + bx + ty + i) * 2048 + by + tx] = tb[tx][ty + i];
    } else {
        int r = blk - 6144;
        transpose_body(Wo, WoT, 2048, 2048, (r & 63) * 32, (r >> 6) * 32, tf, tid);
    }
}

// ---------------------------------------------------------------------------
// Causal GQA flash attention, GROUP-SHARED K/V + XCD-PINNED GROUPS,
// KVBLK=128 fat windows. (byte-identical to round 9 — 81.7 us measured)
// ---------------------------------------------------------------------------
__global__ __launch_bounds__(256, 2) void gqa_attn(
    const bf16_t* __restrict__ Q, const bf16_t* __restrict__ Kc,
    const bf16_t* __restrict__ Vt, bf16_t* __restrict__ AO)
{
    __shared__ alignas(16) bf16_t Ks[2][128 * 64];  // [buf][2x 64x64 swizzled]
    __shared__ alignas(16) bf16_t Vs[2][128 * 64];  // [buf][2x 64d x 64k swz]

    const int bid = blockIdx.x;
    const int l   = (bid & 7) * 64 + (bid >> 3);   // XCD-pinning remap
    const int g   = l >> 6;                        // kv-group == XCD
    const int b   = (l >> 5) & 1;
    const int x   = l & 31;

    const int tid  = threadIdx.x;
    const int wave = tid >> 6, lane = tid & 63;
    const int quad = lane >> 4, l16 = lane & 15;
    const int h = g * 4 + wave;                // each wave owns one head

    #pragma unroll 1
    for (int t = 0; t < 2; ++t) {
        const int qt = t ? x : (63 - x);       // 32-row tile idx, heavy first
        const int q0 = qt * 32;
        int qb[2];
        qb[0] = q0;
        qb[1] = q0 + 16;

        // Q as B-frag (Q^T): lane holds Q[qb+l16][kh*32+quad*8+j], RoPE+scale
        bf16x8 qf[2][2];
        #pragma unroll
        for (int mt = 0; mt < 2; ++mt) {
            int qrow = qb[mt] + l16;
            const bf16_t* qp = Q + (size_t)(b * 2048 + qrow) * 2048 + h * 64 + quad * 8;
            bf16x8 lo = *(const bf16x8*)qp;
            bf16x8 hi = *(const bf16x8*)(qp + 32);
            #pragma unroll
            for (int j = 0; j < 8; ++j) {
                int d = quad * 8 + j;
                float invf = powf(10000.0f, -(float)d / 32.0f);
                float sv, cv;
                sincosf((float)qrow * invf, &sv, &cv);
                float a = (float)lo[j], c2 = (float)hi[j];
                qf[mt][0][j] = (bf16_t)((a * cv - c2 * sv) * SCORE_SCALE);
                qf[mt][1][j] = (bf16_t)((c2 * cv + a * sv) * SCORE_SCALE);
            }
        }

        floatx4 o[2][4] = {};     // O^T: [mt][dt], rows d=quad*4+r, col q=l16
        floatx4 ls4[2] = {};      // lsum partials per q=l16 (4 chains)

        const int ktmax = qt >> 1;             // last valid 64-key tile
        const int nwin  = (ktmax >> 1) + 1;    // 128-key windows

        // stage window `win` (128 keys) into buffer dst: 4 K + 4 V rounds
        auto STAGE = [&](int win, int dst) {
            const int kbase = win * 128;
            #pragma unroll
            for (int i = 0; i < 4; ++i) {       // K rows kbase..kbase+127
                int c = i * 256 + tid, r = c >> 3, s = c & 7;
                int sw = (s ^ (r & 7)) << 3;
                gld16(Kc + (size_t)(b * 2048 + kbase + r) * 512 + g * 64 + sw,
                      &Ks[dst][(i * 256 + wave * 64) * 8]);
            }
            #pragma unroll
            for (int i = 0; i < 4; ++i) {       // V^T: d-rows x 2 key-halves
                int c = i * 256 + tid;
                int ci = c & 511, hw = c >> 9;
                int r = ci >> 3, s = ci & 7;
                int sw = (s ^ (r & 7)) << 3;
                gld16(Vt + (size_t)(b * 512 + g * 64 + r) * 2048
                         + kbase + hw * 64 + sw,
                      &Vs[dst][(i * 256 + wave * 64) * 8]);
            }
        };

        // prologue: buffers free (prev tile drained), prefetch window 0
        __asm__ volatile("s_waitcnt lgkmcnt(0)" ::: "memory");
        __builtin_amdgcn_s_barrier();
        STAGE(0, 0);

        #pragma unroll 1
        for (int win = 0; win < nwin; ++win) {
            const int cur = win & 1;
            if (win + 1 < nwin) {
                STAGE(win + 1, cur ^ 1);
                __asm__ volatile("s_waitcnt vmcnt(8)" ::: "memory");
            } else {
                __asm__ volatile("s_waitcnt vmcnt(0)" ::: "memory");
            }
            __builtin_amdgcn_s_barrier();   // buf[cur] fully landed

            #pragma unroll
            for (int hw = 0; hw < 2; ++hw) {
                const int kt = 2 * win + hw;
                if (kt <= ktmax) {
                    const bf16_t* Ksh = &Ks[cur][hw * 4096];
                    const bf16_t* Vsh = &Vs[cur][hw * 4096];

                    // S^T = K.Q^T
                    floatx4 st[2][4] = {};
                    __builtin_amdgcn_s_setprio(1);
                    #pragma unroll
                    for (int nt = 0; nt < 4; ++nt) {
                        int kr = nt * 16 + l16;
                        bf16x8 kf0 = *(const bf16x8*)&Ksh[kr * 64 + ((quad ^ (kr & 7)) << 3)];
                        bf16x8 kf1 = *(const bf16x8*)&Ksh[kr * 64 + (((4 + quad) ^ (kr & 7)) << 3)];
                        st[0][nt] = MFMA16(kf0, qf[0][0], st[0][nt]);
                        st[0][nt] = MFMA16(kf1, qf[0][1], st[0][nt]);
                        st[1][nt] = MFMA16(kf0, qf[1][0], st[1][nt]);
                        st[1][nt] = MFMA16(kf1, qf[1][1], st[1][nt]);
                    }
                    __builtin_amdgcn_s_setprio(0);

                    // exp2 + causal mask (diag tile only) + lsum + pack P^T
                    PU pk[2][4];
                    const bool diag = (kt == ktmax);
                    #pragma unroll
                    for (int mt = 0; mt < 2; ++mt) {
                        const int qa = qb[mt] + l16;
                        #pragma unroll
                        for (int nt = 0; nt < 4; ++nt) {
                            float pv[4];
                            #pragma unroll
                            for (int r = 0; r < 4; ++r) {
                                float e = PEXP(st[mt][nt][r]);
                                if (diag) {
                                    int ka = kt * 64 + nt * 16 + quad * 4 + r;
                                    if (ka > qa) e = 0.f;
                                }
                                ls4[mt][r] += e;
                                pv[r] = e;
                            }
                            pk[mt][nt].v = bf16x4{(bf16_t)pv[0], (bf16_t)pv[1],
                                                  (bf16_t)pv[2], (bf16_t)pv[3]};
                        }
                    }

#ifdef HAVE_MFMA_K16
                    // O^T += V^T.P^T  (P^T straight from registers)
                    __builtin_amdgcn_s_setprio(1);
                    #pragma unroll
                    for (int nt = 0; nt < 4; ++nt)
                        #pragma unroll
                        for (int dt = 0; dt < 4; ++dt) {
                            int vr = dt * 16 + l16;
                            int slot = ((nt << 1) | (quad >> 1)) ^ (vr & 7);
                            bf16x4 va = *(const bf16x4*)&Vsh[vr * 64 + (slot << 3)
                                                             + ((quad & 1) << 2)];
                            o[0][dt] = mfma_k16(va, pk[0][nt].v, o[0][dt]);
                            o[1][dt] = mfma_k16(va, pk[1][nt].v, o[1][dt]);
                        }
                    __builtin_amdgcn_s_setprio(0);
#else
                    #pragma unroll
                    for (int H = 0; H < 2; ++H) {
                        BU bfv[2];
                        #pragma unroll
                        for (int mt = 0; mt < 2; ++mt) {
                            #pragma unroll
                            for (int j = 0; j < 4; ++j) {
                                int srcl = (((quad & 1) << 1) + (j >> 1)) * 16 + l16;
                                unsigned a0 = (unsigned)__shfl((int)pk[mt][2 * H].u[j & 1], srcl, 64);
                                unsigned a1 = (unsigned)__shfl((int)pk[mt][2 * H + 1].u[j & 1], srcl, 64);
                                bfv[mt].u[j] = (quad >> 1) ? a1 : a0;
                            }
                        }
                        #pragma unroll
                        for (int dt = 0; dt < 4; ++dt) {
                            int vr = dt * 16 + l16;
                            bf16x8 va = *(const bf16x8*)&Vsh[vr * 64
                                          + ((((H << 2) | quad) ^ (vr & 7)) << 3)];
                            o[0][dt] = MFMA16(va, bfv[0].v, o[0][dt]);
                            o[1][dt] = MFMA16(va, bfv[1].v, o[1][dt]);
                        }
                    }
#endif
                }
            }

            // reads of buf[cur] retired before anyone overwrites it
            __asm__ volatile("s_waitcnt lgkmcnt(0)" ::: "memory");
            __builtin_amdgcn_s_barrier();
        }

        // epilogue: finish lsum (sum 4 chains + quad reduce), divide, store
        #pragma unroll
        for (int mt = 0; mt < 2; ++mt) {
            float l2 = ls4[mt][0] + ls4[mt][1] + ls4[mt][2] + ls4[mt][3];
            l2 += __shfl_xor(l2, 16, 64);
            l2 += __shfl_xor(l2, 32, 64);
            float rc = 1.0f / l2;
            #pragma unroll
            for (int dt = 0; dt < 4; ++dt) {
                bf16x4 ov = {(bf16_t)(o[mt][dt][0] * rc), (bf16_t)(o[mt][dt][1] * rc),
                             (bf16_t)(o[mt][dt][2] * rc), (bf16_t)(o[mt][dt][3] * rc)};
                *(bf16x4*)&AO[(size_t)(b * 2048 + qb[mt] + l16) * 2048
                              + h * 64 + dt * 16 + quad * 4] = ov;
            }
        }
    }
}

// ---------------------------------------------------------------------------
extern "C" void kernel_launch(void* const* d_in, const int* in_sizes, int n_in,
                              void* d_out, int out_size, void* d_ws, size_t ws_size,
                              hipStream_t stream)
{
    const float* x  = (const float*)d_in[0];
    const float* Wq = (const float*)d_in[1];
    const float* Wk = (const float*)d_in[2];
    const float* Wv = (const float*)d_in[3];
    const float* Wo = (const float*)d_in[4];
    float* out = (float*)d_out;

    const size_t MB = 1024 * 1024;
    char* ws = (char*)d_ws;
    bf16_t* xb_AO = (bf16_t*)(ws);              // 16 MiB: xb, later AO
    bf16_t* WqoT  = (bf16_t*)(ws + 16 * MB);    //  8 MiB: Wq^T, later Wo^T
    bf16_t* WkT   = (bf16_t*)(ws + 24 * MB);    //  2 MiB
    bf16_t* WvT   = (bf16_t*)(ws + 26 * MB);    //  2 MiB
    bf16_t* Qw    = (bf16_t*)(ws + 28 * MB);    // 16 MiB
    bf16_t* Kw    = (bf16_t*)(ws + 44 * MB);    //  4 MiB
    bf16_t* Vw    = (bf16_t*)(ws + 48 * MB);    //  4 MiB
    bf16_t* VtG   = (bf16_t*)(ws + 52 * MB);    //  4 MiB

    // one-time: 64 KiB dynamic LDS on the 128-tile GEMMs (2 blocks/CU)
    static bool s_attr = false;
    if (!s_attr) {
        hipFuncSetAttribute(reinterpret_cast<const void*>(gemm128_qkv),
                            hipFuncAttributeMaxDynamicSharedMemorySize, 65536);
        hipFuncSetAttribute(reinterpret_cast<const void*>(gemm128_out),
                            hipFuncAttributeMaxDynamicSharedMemorySize, 65536);
        s_attr = true;
    }

    // 1) prep: x->bf16, Wq/Wk/Wv -> transposed bf16
    prep_all<<<14336, 256, 0, stream>>>(x, Wq, Wk, Wv, xb_AO, WqoT, WkT, WvT);

    // 2) fused QKV projection (128x128 tiles, 24x32 grid = 768 blocks)
    gemm128_qkv<<<dim3(24, 32), 256, 65536, stream>>>(
        xb_AO, WqoT, WkT, WvT, Qw, Kw, Vw);

    // 3) RoPE(K) + V->V^T + Wo^T (Wo^T reuses Wq^T region, dead after QKV)
    mid_all<<<10240, 256, 0, stream>>>(Kw, Vw, VtG, Wo, WqoT);

    // 4) attention: group-shared K/V, XCD-pinned, 128-key fat windows
    gqa_attn<<<dim3(512), 256, 0, stream>>>(Qw, Kw, VtG, xb_AO);

    // 5) output projection (128x128 tiles, 16x32 grid = 512 blocks, fp32 out)
    gemm128_out<<<dim3(16, 32), 256, 65536, stream>>>(xb_AO, WqoT, out);
}

// Round 12
// 274.701 us; speedup vs baseline: 1.0896x; 1.0487x over previous
//
#include <hip/hip_runtime.h>
#include <math.h>

typedef __bf16 bf16_t;
typedef bf16_t bf16x8 __attribute__((ext_vector_type(8)));
typedef bf16_t bf16x4 __attribute__((ext_vector_type(4)));
typedef float floatx4 __attribute__((ext_vector_type(4)));
typedef short short4v __attribute__((ext_vector_type(4)));

#define MFMA16(a, b, c) __builtin_amdgcn_mfma_f32_16x16x32_bf16((a), (b), (c), 0, 0, 0)

#if __has_builtin(__builtin_amdgcn_exp2f)
#define PEXP(x) __builtin_amdgcn_exp2f(x)
#define SCORE_SCALE (0.125f * 1.4426950408889634f)   // fold log2e into Q scale
#else
#define PEXP(x) __expf(x)
#define SCORE_SCALE 0.125f
#endif

#if __has_builtin(__builtin_amdgcn_mfma_f32_16x16x16bf16_1k)
#define HAVE_MFMA_K16 1
__device__ __forceinline__ floatx4 mfma_k16(bf16x4 a, bf16x4 b, floatx4 c)
{
    union { bf16x4 v; short4v s; } ua, ub;
    ua.v = a; ub.v = b;
    return __builtin_amdgcn_mfma_f32_16x16x16bf16_1k(ua.s, ub.s, c, 0, 0, 0);
}
#endif

union PU { unsigned u[2]; bf16x4 v; };
union BU { unsigned u[4]; bf16x8 v; };

// global -> LDS direct copy, 16 B per lane (wave-uniform LDS base + lane*16).
__device__ __forceinline__ void gld16(const void* g, void* lds)
{
    __builtin_amdgcn_global_load_lds(
        reinterpret_cast<const __attribute__((address_space(1))) void*>(
            reinterpret_cast<uintptr_t>(g)),
        reinterpret_cast<__attribute__((address_space(3))) void*>(
            (unsigned int)reinterpret_cast<uintptr_t>(lds)),
        16, 0, 0);
}

template <int N>
__device__ __forceinline__ void vmw()
{
    __asm__ volatile("s_waitcnt vmcnt(%0)" :: "n"(N) : "memory");
}

__device__ __forceinline__ void barx()
{
    __asm__ volatile("" ::: "memory");
    __builtin_amdgcn_s_barrier();
    __asm__ volatile("" ::: "memory");
}

__device__ __forceinline__ void lgk0()
{
    __asm__ volatile("s_waitcnt lgkmcnt(0)" ::: "memory");
}

// ---------------------------------------------------------------------------
// 128x128-tile GEMM, 256 threads (4 waves 2x2), BK=64, double-buffered,
// counted vmcnt. C[M,N]=A[M,K]@Bt[N,K]^T. LDS = 64 KB -> 2 blocks/CU.
// NEW (r12): XCD-aware block swizzle (T1). Default round-robin puts the 8
// consecutive blocks that share an A-panel on 8 different XCDs, so each
// XCD L2 must hold the whole A+B working set (28 MB >> 4 MB) -> thrash
// (r8 observed 102 MB FETCH vs 26 MB inputs). Flat grid + bijective remap
// l=(bid&7)*chunk+(bid>>3) gives each XCD a contiguous x-fastest chunk:
// 4 A-panels (2 MB, L2-resident) + B-slices streamed in K-lockstep.
// Per K-tile: {stage(u+1)->other buf (8 gld16) -> vmcnt(8) -> barrier ->
// 16 ds_read_b128 -> setprio 32 MFMA -> lgkmcnt(0) -> barrier}.
// ---------------------------------------------------------------------------
__device__ __forceinline__ void stage128(
    const bf16_t* __restrict__ g, int K, int r0, int k0,
    bf16_t* lds, int tid, int wave)
{
    #pragma unroll
    for (int i = 0; i < 4; ++i) {
        int c = i * 256 + tid, r = c >> 3, s = c & 7;
        gld16(g + (size_t)(r0 + r) * K + k0 + ((s ^ (r & 7)) << 3),
              lds + (size_t)(i * 256 + wave * 64) * 8);
    }
}

template <typename TC>
__device__ __forceinline__ void gemm128_body(
    const bf16_t* __restrict__ A, const bf16_t* __restrict__ Bt,
    TC* __restrict__ C, int row0, int col0, int N, int K, bf16_t* smem)
{
    const int tid  = threadIdx.x;
    const int wave = tid >> 6, lane = tid & 63;
    const int quad = lane >> 4, l16 = lane & 15;
    const int wm = (wave >> 1) * 64;
    const int wn = (wave & 1) * 64;

    bf16_t* As0 = smem;             // 128*64 each
    bf16_t* As1 = smem + 8192;
    bf16_t* Bs0 = smem + 16384;
    bf16_t* Bs1 = smem + 24576;

    const int ntile = K >> 6;

    floatx4 acc[4][4] = {};

    // prologue: tile 0 -> buf 0 (8 loads)
    stage128(A, K, row0, 0, As0, tid, wave);
    stage128(Bt, K, col0, 0, Bs0, tid, wave);

    #pragma unroll 1
    for (int u = 0; u < ntile; ++u) {
        const int d = u & 1;
        bf16_t* Asd = d ? As1 : As0;
        bf16_t* Bsd = d ? Bs1 : Bs0;

        if (u + 1 < ntile) {
            stage128(A, K, row0, (u + 1) << 6, d ? As0 : As1, tid, wave);
            stage128(Bt, K, col0, (u + 1) << 6, d ? Bs0 : Bs1, tid, wave);
            vmw<8>();               // tile u landed; tile u+1's 8 in flight
        } else {
            vmw<0>();
        }
        barx();                     // landed for ALL waves

        bf16x8 af[4][2], bfr[4][2];
        #pragma unroll
        for (int mt = 0; mt < 4; ++mt)
            #pragma unroll
            for (int kh = 0; kh < 2; ++kh) {
                int ar = wm + mt * 16 + l16;
                af[mt][kh] = *(const bf16x8*)&Asd[ar * 64 +
                    (((kh * 4 + quad) ^ (ar & 7)) << 3)];
            }
        #pragma unroll
        for (int nt = 0; nt < 4; ++nt)
            #pragma unroll
            for (int kh = 0; kh < 2; ++kh) {
                int br = wn + nt * 16 + l16;
                bfr[nt][kh] = *(const bf16x8*)&Bsd[br * 64 +
                    (((kh * 4 + quad) ^ (br & 7)) << 3)];
            }

        __builtin_amdgcn_s_setprio(1);
        #pragma unroll
        for (int kh = 0; kh < 2; ++kh)
            #pragma unroll
            for (int mt = 0; mt < 4; ++mt)
                #pragma unroll
                for (int nt = 0; nt < 4; ++nt)
                    acc[mt][nt] = MFMA16(af[mt][kh], bfr[nt][kh], acc[mt][nt]);
        __builtin_amdgcn_s_setprio(0);

        lgk0();                     // all LDS reads of buf[cur] retired
        barx();
    }

    #pragma unroll
    for (int mt = 0; mt < 4; ++mt)
        #pragma unroll
        for (int nt = 0; nt < 4; ++nt)
            #pragma unroll
            for (int r = 0; r < 4; ++r)
                C[(size_t)(row0 + wm + mt * 16 + quad * 4 + r) * N
                  + col0 + wn + nt * 16 + l16] = (TC)acc[mt][nt][r];
}

// Fused Q+K+V projection. Flat grid 768 = 24 col-tiles x 32 row-tiles,
// XCD-swizzled: each XCD owns a 96-block chunk (24 x-tiles x 4 y-rows).
// x<16 -> Q, x<20 -> K, else V.
__global__ __launch_bounds__(256, 2) void gemm128_qkv(
    const bf16_t* __restrict__ A, const bf16_t* __restrict__ BtQ,
    const bf16_t* __restrict__ BtK, const bf16_t* __restrict__ BtV,
    bf16_t* __restrict__ CQ, bf16_t* __restrict__ CK, bf16_t* __restrict__ CV)
{
    extern __shared__ __align__(16) bf16_t smem[];
    const int bid = blockIdx.x;
    const int l = (bid & 7) * 96 + (bid >> 3);   // bijective (768 = 8*96)
    const int x = l % 24;
    const int y = l / 24;
    const bf16_t* Bt; bf16_t* C; int N, col0;
    if (x < 16)      { Bt = BtQ; C = CQ; N = 2048; col0 = x * 128; }
    else if (x < 20) { Bt = BtK; C = CK; N = 512;  col0 = (x - 16) * 128; }
    else             { Bt = BtV; C = CV; N = 512;  col0 = (x - 20) * 128; }
    gemm128_body<bf16_t>(A, Bt, C, y * 128, col0, N, 2048, smem);
}

// Output projection: flat 512 = 16 col-tiles x 32 row-tiles, XCD-swizzled
// (64-block chunk = 16 x-tiles x 4 y-rows). fp32 out.
__global__ __launch_bounds__(256, 2) void gemm128_out(
    const bf16_t* __restrict__ A, const bf16_t* __restrict__ Bt,
    float* __restrict__ C)
{
    extern __shared__ __align__(16) bf16_t smem[];
    const int bid = blockIdx.x;
    const int l = (bid & 7) * 64 + (bid >> 3);   // bijective (512 = 8*64)
    const int x = l & 15;
    const int y = l >> 4;
    gemm128_body<float>(A, Bt, C, y * 128, x * 128, 2048, 2048, smem);
}

// ---------------------------------------------------------------------------
// Fused prep: x->bf16 conversion + Wq/Wk/Wv fp32->bf16 transposes.
// grid: [0,8192) conv, [8192,12288) Wq, [12288,13312) Wk, [13312,14336) Wv
// ---------------------------------------------------------------------------
__device__ __forceinline__ void transpose_body(
    const float* __restrict__ W, bf16_t* __restrict__ Wt, int K, int N,
    int bx, int by, float (*t)[33], int tid)
{
    int tx = tid & 31, ty = tid >> 5;
    #pragma unroll
    for (int i = 0; i < 32; i += 8)
        t[ty + i][tx] = W[(size_t)(by + ty + i) * N + bx + tx];
    __syncthreads();
    #pragma unroll
    for (int i = 0; i < 32; i += 8)
        Wt[(size_t)(bx + ty + i) * K + by + tx] = (bf16_t)t[tx][ty + i];
}

__global__ __launch_bounds__(256) void prep_all(
    const float* __restrict__ x, const float* __restrict__ Wq,
    const float* __restrict__ Wk, const float* __restrict__ Wv,
    bf16_t* __restrict__ xb, bf16_t* __restrict__ WqT,
    bf16_t* __restrict__ WkT, bf16_t* __restrict__ WvT)
{
    __shared__ float t[32][33];
    const int blk = blockIdx.x, tid = threadIdx.x;
    if (blk < 8192) {
        int i = blk * 256 + tid;
        float4 f = ((const float4*)x)[i];
        bf16x4 v = {(bf16_t)f.x, (bf16_t)f.y, (bf16_t)f.z, (bf16_t)f.w};
        ((bf16x4*)xb)[i] = v;
    } else if (blk < 12288) {
        int r = blk - 8192;
        transpose_body(Wq, WqT, 2048, 2048, (r & 63) * 32, (r >> 6) * 32, t, tid);
    } else if (blk < 13312) {
        int r = blk - 12288;
        transpose_body(Wk, WkT, 2048, 512, (r & 15) * 32, (r >> 4) * 32, t, tid);
    } else {
        int r = blk - 13312;
        transpose_body(Wv, WvT, 2048, 512, (r & 15) * 32, (r >> 4) * 32, t, tid);
    }
}

// ---------------------------------------------------------------------------
// Fused mid: RoPE(K) + V-transpose + Wo-transpose.
// grid: [0,4096) rope, [4096,6144) V^T, [6144,10240) Wo
// ---------------------------------------------------------------------------
__global__ __launch_bounds__(256) void mid_all(
    bf16_t* __restrict__ Kw, const bf16_t* __restrict__ Vw,
    bf16_t* __restrict__ VtG, const float* __restrict__ Wo,
    bf16_t* __restrict__ WoT)
{
    __shared__ float tf[32][33];
    __shared__ bf16_t tb[32][34];
    const int blk = blockIdx.x, tid = threadIdx.x;
    if (blk < 4096) {
        int idx = blk * 256 + tid;
        int i   = idx & 31;
        int h   = (idx >> 5) & 7;
        int row = idx >> 8;
        int pos = row & 2047;
        float invf = powf(10000.0f, -(float)i / 32.0f);
        float sv, cv;
        sincosf((float)pos * invf, &sv, &cv);
        size_t base = (size_t)row * 512 + (size_t)h * 64 + i;
        float a  = (float)Kw[base];
        float b2 = (float)Kw[base + 32];
        Kw[base]      = (bf16_t)(a * cv - b2 * sv);
        Kw[base + 32] = (bf16_t)(b2 * cv + a * sv);
    } else if (blk < 6144) {
        int r  = blk - 4096;
        int bz = r >> 10, r2 = r & 1023;
        int bx = (r2 & 15) * 32, by = (r2 >> 4) * 32;
        int tx = tid & 31, ty = tid >> 5;
        #pragma unroll
        for (int i = 0; i < 32; i += 8)
            tb[ty + i][tx] = Vw[((size_t)bz * 2048 + by + ty + i) * 512 + bx + tx];
        __syncthreads();
        #pragma unroll
        for (int i = 0; i < 32; i += 8)
            VtG[((size_t)bz * 512 + bx + ty + i) * 2048 + by + tx] = tb[tx][ty + i];
    } else {
        int r = blk - 6144;
        transpose_body(Wo, WoT, 2048, 2048, (r & 63) * 32, (r >> 6) * 32, tf, tid);
    }
}

// ---------------------------------------------------------------------------
// Causal GQA flash attention, GROUP-SHARED K/V + XCD-PINNED GROUPS,
// KVBLK=128 fat windows. (byte-identical to rounds 9-11 — 81.4-82.0 us)
// ---------------------------------------------------------------------------
__global__ __launch_bounds__(256, 2) void gqa_attn(
    const bf16_t* __restrict__ Q, const bf16_t* __restrict__ Kc,
    const bf16_t* __restrict__ Vt, bf16_t* __restrict__ AO)
{
    __shared__ alignas(16) bf16_t Ks[2][128 * 64];  // [buf][2x 64x64 swizzled]
    __shared__ alignas(16) bf16_t Vs[2][128 * 64];  // [buf][2x 64d x 64k swz]

    const int bid = blockIdx.x;
    const int l   = (bid & 7) * 64 + (bid >> 3);   // XCD-pinning remap
    const int g   = l >> 6;                        // kv-group == XCD
    const int b   = (l >> 5) & 1;
    const int x   = l & 31;

    const int tid  = threadIdx.x;
    const int wave = tid >> 6, lane = tid & 63;
    const int quad = lane >> 4, l16 = lane & 15;
    const int h = g * 4 + wave;                // each wave owns one head

    #pragma unroll 1
    for (int t = 0; t < 2; ++t) {
        const int qt = t ? x : (63 - x);       // 32-row tile idx, heavy first
        const int q0 = qt * 32;
        int qb[2];
        qb[0] = q0;
        qb[1] = q0 + 16;

        // Q as B-frag (Q^T): lane holds Q[qb+l16][kh*32+quad*8+j], RoPE+scale
        bf16x8 qf[2][2];
        #pragma unroll
        for (int mt = 0; mt < 2; ++mt) {
            int qrow = qb[mt] + l16;
            const bf16_t* qp = Q + (size_t)(b * 2048 + qrow) * 2048 + h * 64 + quad * 8;
            bf16x8 lo = *(const bf16x8*)qp;
            bf16x8 hi = *(const bf16x8*)(qp + 32);
            #pragma unroll
            for (int j = 0; j < 8; ++j) {
                int d = quad * 8 + j;
                float invf = powf(10000.0f, -(float)d / 32.0f);
                float sv, cv;
                sincosf((float)qrow * invf, &sv, &cv);
                float a = (float)lo[j], c2 = (float)hi[j];
                qf[mt][0][j] = (bf16_t)((a * cv - c2 * sv) * SCORE_SCALE);
                qf[mt][1][j] = (bf16_t)((c2 * cv + a * sv) * SCORE_SCALE);
            }
        }

        floatx4 o[2][4] = {};     // O^T: [mt][dt], rows d=quad*4+r, col q=l16
        floatx4 ls4[2] = {};      // lsum partials per q=l16 (4 chains)

        const int ktmax = qt >> 1;             // last valid 64-key tile
        const int nwin  = (ktmax >> 1) + 1;    // 128-key windows

        // stage window `win` (128 keys) into buffer dst: 4 K + 4 V rounds
        auto STAGE = [&](int win, int dst) {
            const int kbase = win * 128;
            #pragma unroll
            for (int i = 0; i < 4; ++i) {       // K rows kbase..kbase+127
                int c = i * 256 + tid, r = c >> 3, s = c & 7;
                int sw = (s ^ (r & 7)) << 3;
                gld16(Kc + (size_t)(b * 2048 + kbase + r) * 512 + g * 64 + sw,
                      &Ks[dst][(i * 256 + wave * 64) * 8]);
            }
            #pragma unroll
            for (int i = 0; i < 4; ++i) {       // V^T: d-rows x 2 key-halves
                int c = i * 256 + tid;
                int ci = c & 511, hw = c >> 9;
                int r = ci >> 3, s = ci & 7;
                int sw = (s ^ (r & 7)) << 3;
                gld16(Vt + (size_t)(b * 512 + g * 64 + r) * 2048
                         + kbase + hw * 64 + sw,
                      &Vs[dst][(i * 256 + wave * 64) * 8]);
            }
        };

        // prologue: buffers free (prev tile drained), prefetch window 0
        __asm__ volatile("s_waitcnt lgkmcnt(0)" ::: "memory");
        __builtin_amdgcn_s_barrier();
        STAGE(0, 0);

        #pragma unroll 1
        for (int win = 0; win < nwin; ++win) {
            const int cur = win & 1;
            if (win + 1 < nwin) {
                STAGE(win + 1, cur ^ 1);
                __asm__ volatile("s_waitcnt vmcnt(8)" ::: "memory");
            } else {
                __asm__ volatile("s_waitcnt vmcnt(0)" ::: "memory");
            }
            __builtin_amdgcn_s_barrier();   // buf[cur] fully landed

            #pragma unroll
            for (int hw = 0; hw < 2; ++hw) {
                const int kt = 2 * win + hw;
                if (kt <= ktmax) {
                    const bf16_t* Ksh = &Ks[cur][hw * 4096];
                    const bf16_t* Vsh = &Vs[cur][hw * 4096];

                    // S^T = K.Q^T
                    floatx4 st[2][4] = {};
                    __builtin_amdgcn_s_setprio(1);
                    #pragma unroll
                    for (int nt = 0; nt < 4; ++nt) {
                        int kr = nt * 16 + l16;
                        bf16x8 kf0 = *(const bf16x8*)&Ksh[kr * 64 + ((quad ^ (kr & 7)) << 3)];
                        bf16x8 kf1 = *(const bf16x8*)&Ksh[kr * 64 + (((4 + quad) ^ (kr & 7)) << 3)];
                        st[0][nt] = MFMA16(kf0, qf[0][0], st[0][nt]);
                        st[0][nt] = MFMA16(kf1, qf[0][1], st[0][nt]);
                        st[1][nt] = MFMA16(kf0, qf[1][0], st[1][nt]);
                        st[1][nt] = MFMA16(kf1, qf[1][1], st[1][nt]);
                    }
                    __builtin_amdgcn_s_setprio(0);

                    // exp2 + causal mask (diag tile only) + lsum + pack P^T
                    PU pk[2][4];
                    const bool diag = (kt == ktmax);
                    #pragma unroll
                    for (int mt = 0; mt < 2; ++mt) {
                        const int qa = qb[mt] + l16;
                        #pragma unroll
                        for (int nt = 0; nt < 4; ++nt) {
                            float pv[4];
                            #pragma unroll
                            for (int r = 0; r < 4; ++r) {
                                float e = PEXP(st[mt][nt][r]);
                                if (diag) {
                                    int ka = kt * 64 + nt * 16 + quad * 4 + r;
                                    if (ka > qa) e = 0.f;
                                }
                                ls4[mt][r] += e;
                                pv[r] = e;
                            }
                            pk[mt][nt].v = bf16x4{(bf16_t)pv[0], (bf16_t)pv[1],
                                                  (bf16_t)pv[2], (bf16_t)pv[3]};
                        }
                    }

#ifdef HAVE_MFMA_K16
                    // O^T += V^T.P^T  (P^T straight from registers)
                    __builtin_amdgcn_s_setprio(1);
                    #pragma unroll
                    for (int nt = 0; nt < 4; ++nt)
                        #pragma unroll
                        for (int dt = 0; dt < 4; ++dt) {
                            int vr = dt * 16 + l16;
                            int slot = ((nt << 1) | (quad >> 1)) ^ (vr & 7);
                            bf16x4 va = *(const bf16x4*)&Vsh[vr * 64 + (slot << 3)
                                                             + ((quad & 1) << 2)];
                            o[0][dt] = mfma_k16(va, pk[0][nt].v, o[0][dt]);
                            o[1][dt] = mfma_k16(va, pk[1][nt].v, o[1][dt]);
                        }
                    __builtin_amdgcn_s_setprio(0);
#else
                    #pragma unroll
                    for (int H = 0; H < 2; ++H) {
                        BU bfv[2];
                        #pragma unroll
                        for (int mt = 0; mt < 2; ++mt) {
                            #pragma unroll
                            for (int j = 0; j < 4; ++j) {
                                int srcl = (((quad & 1) << 1) + (j >> 1)) * 16 + l16;
                                unsigned a0 = (unsigned)__shfl((int)pk[mt][2 * H].u[j & 1], srcl, 64);
                                unsigned a1 = (unsigned)__shfl((int)pk[mt][2 * H + 1].u[j & 1], srcl, 64);
                                bfv[mt].u[j] = (quad >> 1) ? a1 : a0;
                            }
                        }
                        #pragma unroll
                        for (int dt = 0; dt < 4; ++dt) {
                            int vr = dt * 16 + l16;
                            bf16x8 va = *(const bf16x8*)&Vsh[vr * 64
                                          + ((((H << 2) | quad) ^ (vr & 7)) << 3)];
                            o[0][dt] = MFMA16(va, bfv[0].v, o[0][dt]);
                            o[1][dt] = MFMA16(va, bfv[1].v, o[1][dt]);
                        }
                    }
#endif
                }
            }

            // reads of buf[cur] retired before anyone overwrites it
            __asm__ volatile("s_waitcnt lgkmcnt(0)" ::: "memory");
            __builtin_amdgcn_s_barrier();
        }

        // epilogue: finish lsum (sum 4 chains + quad reduce), divide, store
        #pragma unroll
        for (int mt = 0; mt < 2; ++mt) {
            float l2 = ls4[mt][0] + ls4[mt][1] + ls4[mt][2] + ls4[mt][3];
            l2 += __shfl_xor(l2, 16, 64);
            l2 += __shfl_xor(l2, 32, 64);
            float rc = 1.0f / l2;
            #pragma unroll
            for (int dt = 0; dt < 4; ++dt) {
                bf16x4 ov = {(bf16_t)(o[mt][dt][0] * rc), (bf16_t)(o[mt][dt][1] * rc),
                             (bf16_t)(o[mt][dt][2] * rc), (bf16_t)(o[mt][dt][3] * rc)};
                *(bf16x4*)&AO[(size_t)(b * 2048 + qb[mt] + l16) * 2048
                              + h * 64 + dt * 16 + quad * 4] = ov;
            }
        }
    }
}

// ---------------------------------------------------------------------------
extern "C" void kernel_launch(void* const* d_in, const int* in_sizes, int n_in,
                              void* d_out, int out_size, void* d_ws, size_t ws_size,
                              hipStream_t stream)
{
    const float* x  = (const float*)d_in[0];
    const float* Wq = (const float*)d_in[1];
    const float* Wk = (const float*)d_in[2];
    const float* Wv = (const float*)d_in[3];
    const float* Wo = (const float*)d_in[4];
    float* out = (float*)d_out;

    const size_t MB = 1024 * 1024;
    char* ws = (char*)d_ws;
    bf16_t* xb_AO = (bf16_t*)(ws);              // 16 MiB: xb, later AO
    bf16_t* WqoT  = (bf16_t*)(ws + 16 * MB);    //  8 MiB: Wq^T, later Wo^T
    bf16_t* WkT   = (bf16_t*)(ws + 24 * MB);    //  2 MiB
    bf16_t* WvT   = (bf16_t*)(ws + 26 * MB);    //  2 MiB
    bf16_t* Qw    = (bf16_t*)(ws + 28 * MB);    // 16 MiB
    bf16_t* Kw    = (bf16_t*)(ws + 44 * MB);    //  4 MiB
    bf16_t* Vw    = (bf16_t*)(ws + 48 * MB);    //  4 MiB
    bf16_t* VtG   = (bf16_t*)(ws + 52 * MB);    //  4 MiB

    // one-time: 64 KiB dynamic LDS on the 128-tile GEMMs (2 blocks/CU)
    static bool s_attr = false;
    if (!s_attr) {
        hipFuncSetAttribute(reinterpret_cast<const void*>(gemm128_qkv),
                            hipFuncAttributeMaxDynamicSharedMemorySize, 65536);
        hipFuncSetAttribute(reinterpret_cast<const void*>(gemm128_out),
                            hipFuncAttributeMaxDynamicSharedMemorySize, 65536);
        s_attr = true;
    }

    // 1) prep: x->bf16, Wq/Wk/Wv -> transposed bf16
    prep_all<<<14336, 256, 0, stream>>>(x, Wq, Wk, Wv, xb_AO, WqoT, WkT, WvT);

    // 2) fused QKV projection (128x128 tiles, flat 768, XCD-swizzled)
    gemm128_qkv<<<dim3(768), 256, 65536, stream>>>(
        xb_AO, WqoT, WkT, WvT, Qw, Kw, Vw);

    // 3) RoPE(K) + V->V^T + Wo^T (Wo^T reuses Wq^T region, dead after QKV)
    mid_all<<<10240, 256, 0, stream>>>(Kw, Vw, VtG, Wo, WqoT);

    // 4) attention: group-shared K/V, XCD-pinned, 128-key fat windows
    gqa_attn<<<dim3(512), 256, 0, stream>>>(Qw, Kw, VtG, xb_AO);

    // 5) output projection (128x128 tiles, flat 512, XCD-swizzled, fp32 out)
    gemm128_out<<<dim3(512), 256, 65536, stream>>>(xb_AO, WqoT, out);
}